// Round 3
// baseline (307.163 us; speedup 1.0000x reference)
//
#include <hip/hip_runtime.h>

// CTC loss forward, T=1024, B=128, C=256, S=128, L=2S+1=257.
// One wave per batch; lane l owns O[2l],O[2l+1] (odd states, labels y[2l],
// y[2l+1]) and E[2l],E[2l+1] (blanks). E[128] is a pure sink: every lane runs
// its recursion on the LOCAL Ob (only lane 63's copy is real; broadcast once
// at the end) -- this removes one of the two per-step cross-lane shuffles.
// The remaining shfl_up(Ob) is issued for the NEXT step right after Ob is
// produced, hiding DS latency behind a full step of math.
// FP64 exp-domain states (708-nat range vs ~500-nat worst-case state spread;
// f32's 87 nats dropped samples in R1). Fixed 2^9 bias folded into the exp2
// argument centers the per-step decay; exact power-of-2 wave renorm every 16
// steps. 8-deep register prefetch of the 3 gathered log-probs per step.

#define PF 8
#define CTC_C 256
#define EXP_BIAS 9.0f                 // each prob scaled by 2^9 inside exp2
#define LOG2E 1.4426950408889634f
#define LN2 0.6931471805599453

__global__ __launch_bounds__(64)
void ctc_fwd(const float* __restrict__ lp, const int* __restrict__ y,
             const int* __restrict__ ilen, const int* __restrict__ tlen,
             float* __restrict__ out, int T, int B, int S) {
  const int b = blockIdx.x;
  const int l = threadIdx.x;            // 0..63
  const size_t rowstride = (size_t)B * CTC_C;

  const int len = ilen[b];
  const int tl  = tlen[b];

  const int ya = y[(size_t)b * S + 2 * l];
  const int yb = y[(size_t)b * S + 2 * l + 1];
  const int yprev = __shfl_up(yb, 1);               // y[2l-1]; garbage on lane 0
  const double maskA = (ya != yprev) ? 1.0 : 0.0;   // lane0 ok: its Opm1 is 0
  const double maskB = (yb != ya) ? 1.0 : 0.0;

  // t=0 init: alpha[0]=exp(lp0[blank]) -> E[0]; alpha[1]=exp(lp0[y0]) -> O[0]
  const float* row0 = lp + (size_t)b * CTC_C;
  const int y0 = y[(size_t)b * S];
  double Ea = (l == 0) ? (double)__expf(row0[0])  : 0.0;
  double Oa = (l == 0) ? (double)__expf(row0[y0]) : 0.0;
  double Eb = 0.0, Ob = 0.0, E128 = 0.0;
  double Opm1 = 0.0;                   // O[2l-1] arriving for the next step
  int e_sum = 0;                       // sum of renorm exponents (exact)

  // 8-deep prefetch of the 3 gathered values per step
  float pA[PF], pB[PF], pQ[PF];
  {
    const float* r = lp + rowstride + (size_t)b * CTC_C;   // row t=1
    const float* rl = lp + (size_t)(T - 1) * rowstride + (size_t)b * CTC_C;
#pragma unroll
    for (int d = 0; d < PF; ++d) {
      const float* rp = (1 + d <= T - 1) ? r : rl;
      pA[d] = rp[ya]; pB[d] = rp[yb]; pQ[d] = rp[0];
      r += rowstride;
    }
  }

  const int nsteps = len - 1;          // steps t = 1..nsteps
  const int nchunks = nsteps / PF;
  const float* rlast = lp + (size_t)(T - 1) * rowstride + (size_t)b * CTC_C;
  const float* rfill = lp + (size_t)(1 + PF) * rowstride + (size_t)b * CTC_C;
  int t0 = 1;

  for (int c = 0; c < nchunks; ++c) {
#pragma unroll
    for (int d = 0; d < PF; ++d) {
      const int t = t0 + d;
      // refill slot d with row t+PF (clamped, wave-uniform select)
      const float* rp = (t + PF <= T - 1) ? rfill : rlast;
      float nA = rp[ya], nB = rp[yb], nQ = rp[0];
      rfill += rowstride;

      float fa = exp2f(fmaf(pA[d], LOG2E, EXP_BIAS));
      float fb = exp2f(fmaf(pB[d], LOG2E, EXP_BIAS));
      float fq = exp2f(fmaf(pQ[d], LOG2E, EXP_BIAS));
      pA[d] = nA; pB[d] = nB; pQ[d] = nQ;
      double pa = (double)fa, pb = (double)fb, pq = (double)fq;

      double nOb = fma(maskB, Oa, Ob + Eb) * pb;
      double up = __shfl_up(nOb, 1);         // for NEXT step: full step of slack
      double nOa = fma(maskA, Opm1, Oa + Ea) * pa;
      double nEa = (Ea + Opm1) * pq;
      double nEb = (Eb + Oa) * pq;
      E128 = (E128 + Ob) * pq;               // local Ob; real only on lane 63
      Oa = nOa; Ob = nOb; Ea = nEa; Eb = nEb;
      Opm1 = (l == 0) ? 0.0 : up;

      if (d == PF - 1 && (c & 1)) {          // renorm every 16 steps
        double m = fmax(fmax(Oa, Ob), fmax(Ea, Eb));
        m = fmax(m, E128);                   // fake E128 >= real is harmless
#pragma unroll
        for (int off = 32; off > 0; off >>= 1)
          m = fmax(m, __shfl_xor(m, off));
        long long bits = __double_as_longlong(m);
        int eb2 = (int)((bits >> 52) & 0x7ff);
        int e = eb2 - 1022;                  // m = f*2^e, f in [0.5,1)
        double s = __longlong_as_double((long long)(2045 - eb2) << 52); // 2^-e
        Oa *= s; Ob *= s; Ea *= s; Eb *= s; E128 *= s; Opm1 *= s;
        e_sum += e;
      }
    }
    t0 += PF;
  }

  // tail: up to PF-1 steps, wave-uniform predicate, no refill, no renorm
#pragma unroll
  for (int d = 0; d < PF; ++d) {
    const int t = t0 + d;
    if (t <= nsteps) {
      float fa = exp2f(fmaf(pA[d], LOG2E, EXP_BIAS));
      float fb = exp2f(fmaf(pB[d], LOG2E, EXP_BIAS));
      float fq = exp2f(fmaf(pQ[d], LOG2E, EXP_BIAS));
      double pa = (double)fa, pb = (double)fb, pq = (double)fq;
      double nOb = fma(maskB, Oa, Ob + Eb) * pb;
      double up = __shfl_up(nOb, 1);
      double nOa = fma(maskA, Opm1, Oa + Ea) * pa;
      double nEa = (Ea + Opm1) * pq;
      double nEb = (Eb + Oa) * pq;
      E128 = (E128 + Ob) * pq;
      Oa = nOa; Ob = nOb; Ea = nEa; Eb = nEb;
      Opm1 = (l == 0) ? 0.0 : up;
    }
  }

  // readout: true alpha = stored * 2^(e_sum - 9*nsteps)
  E128 = __shfl(E128, 63);                   // the real E[128]
  double vEa = __shfl(Ea, (tl >> 1) & 63);
  double vEb = __shfl(Eb, (tl >> 1) & 63);
  double vhi = (tl == S) ? E128 : ((tl & 1) ? vEb : vEa);   // alpha[2*tl]
  const int s2 = tl - 1;
  double vOa = __shfl(Oa, (s2 >> 1) & 63);
  double vOb = __shfl(Ob, (s2 >> 1) & 63);
  double vlo = (s2 & 1) ? vOb : vOa;                        // alpha[2*tl-1]

  double sum = vhi + vlo;
  double loss;
  if (sum > 0.0) {
    double ll = log(sum) + (double)(e_sum - 9 * nsteps) * LN2;
    loss = -ll;
  } else {
    loss = 1e30;                             // -inf likelihood
  }
  if (!(loss < 5.0e8)) loss = 0.0;           // zero_infinity (inf/NaN too)
  float contrib = (float)(loss / (double)tl / (double)B);
  if (l == 0) atomicAdd(out, contrib);
}

extern "C" void kernel_launch(void* const* d_in, const int* in_sizes, int n_in,
                              void* d_out, int out_size, void* d_ws, size_t ws_size,
                              hipStream_t stream) {
  const float* lp   = (const float*)d_in[0];
  const int*   yy   = (const int*)d_in[1];
  const int*   ilen = (const int*)d_in[2];
  const int*   tlen = (const int*)d_in[3];
  float* out = (float*)d_out;

  int B = in_sizes[2];
  int S = in_sizes[1] / B;
  int T = in_sizes[0] / (B * CTC_C);

  hipMemsetAsync(out, 0, sizeof(float), stream);
  ctc_fwd<<<B, 64, 0, stream>>>(lp, yy, ilen, tlen, out, T, B, S);
}